// Round 13
// baseline (335.542 us; speedup 1.0000x reference)
//
#include <hip/hip_runtime.h>

#define NODES_MAX 100000
#define EDGES_MAX 1600000
#define BN 256                                   // nodes per bucket (pow2)
#define NBUCK ((NODES_MAX + BN - 1) / BN)        // 391
#define B_PART 256                               // partition blocks (fixed)
#define SCAN_CHUNK 1024
#define PB 128                                   // perm partition blocks
#define DBIN 64                                  // degree bins (cap 63)

// fp32 scratch (r/h tables): r1:0(32) h1:N*32(32) r2:N*64(48) h2:N*112(48)
__device__ float g_ws[(size_t)NODES_MAX * 160];
// bf16 t-tables: t1:0 (32/node) | t2:N*32 (64/node, 48 used: 128B-aligned rows) | t3:N*96 (16/node)
__device__ unsigned short g_tb[(size_t)NODES_MAX * 112];
__device__ int g_rowptr[NODES_MAX + 1];
__device__ int g_csr[EDGES_MAX];            // src ids grouped by dst
__device__ unsigned g_be[EDGES_MAX];        // bucket-ordered packed (src<<8)|local_dst
__device__ int g_mat[NBUCK * B_PART];       // per-(bucket,block) counts -> local-excl prefixes
__device__ int g_bsum[(NBUCK * B_PART + SCAN_CHUNK - 1) / SCAN_CHUNK + 1];
__device__ int g_dmat[DBIN * PB];           // degree-sort partition matrix
__device__ int g_perm[NODES_MAX];           // nodes sorted by degree

__device__ __forceinline__ unsigned short f2bf(float f) {
    union { float f; unsigned u; } c; c.f = f;
    unsigned r = (c.u + 0x7FFFu + ((c.u >> 16) & 1u)) >> 16;
    return (unsigned short)r;
}
__device__ __forceinline__ float bflo(unsigned u) {
    union { unsigned u; float f; } c; c.u = u << 16; return c.f;
}
__device__ __forceinline__ float bfhi(unsigned u) {
    union { unsigned u; float f; } c; c.u = u & 0xFFFF0000u; return c.f;
}

// ---------------- CSR build (radix partition, no global atomics) ----------------
__global__ __launch_bounds__(1024) void k_bcount(const int* __restrict__ edge, int E,
                                                 int nbuck, int chunk) {
    __shared__ int h[NBUCK];
    for (int i = threadIdx.x; i < nbuck; i += 1024) h[i] = 0;
    __syncthreads();
    const int lo = blockIdx.x * chunk, hi = min(E, lo + chunk);
    for (int e = lo + threadIdx.x; e < hi; e += 1024)
        atomicAdd(&h[edge[E + e] >> 8], 1);
    __syncthreads();
    for (int k = threadIdx.x; k < nbuck; k += 1024)
        g_mat[k * B_PART + blockIdx.x] = h[k];
}

__global__ __launch_bounds__(256) void k_scan_local(int M) {
    __shared__ int ssum[256];
    const int tid = threadIdx.x;
    const int base = blockIdx.x * SCAN_CHUNK + tid * 4;
    int v0 = (base + 0 < M) ? g_mat[base + 0] : 0;
    int v1 = (base + 1 < M) ? g_mat[base + 1] : 0;
    int v2 = (base + 2 < M) ? g_mat[base + 2] : 0;
    int v3 = (base + 3 < M) ? g_mat[base + 3] : 0;
    int s = v0 + v1 + v2 + v3;
    ssum[tid] = s;
    __syncthreads();
    for (int off = 1; off < 256; off <<= 1) {
        int v = (tid >= off) ? ssum[tid - off] : 0;
        __syncthreads();
        ssum[tid] += v;
        __syncthreads();
    }
    int run = ssum[tid] - s;
    if (base + 0 < M) g_mat[base + 0] = run;
    run += v0;
    if (base + 1 < M) g_mat[base + 1] = run;
    run += v1;
    if (base + 2 < M) g_mat[base + 2] = run;
    run += v2;
    if (base + 3 < M) g_mat[base + 3] = run;
    if (tid == 255) g_bsum[blockIdx.x] = ssum[255];
}

__global__ __launch_bounds__(1024) void k_scan_bsums(int nb) {
    __shared__ int ssum[1024];
    const int tid = threadIdx.x;
    int s = (tid < nb) ? g_bsum[tid] : 0;
    ssum[tid] = s;
    __syncthreads();
    for (int off = 1; off < 1024; off <<= 1) {
        int v = (tid >= off) ? ssum[tid - off] : 0;
        __syncthreads();
        ssum[tid] += v;
        __syncthreads();
    }
    if (tid < nb) g_bsum[tid] = ssum[tid] - s;
}

// Phase 3: re-read chunk, rank via LDS cursors (global offsets folded in here).
__global__ __launch_bounds__(1024) void k_bpart(const int* __restrict__ edge, int E,
                                                int nbuck, int chunk) {
    __shared__ int cur[NBUCK];
    for (int k = threadIdx.x; k < nbuck; k += 1024) {
        int idx = k * B_PART + blockIdx.x;
        cur[k] = g_mat[idx] + g_bsum[idx >> 10];
    }
    __syncthreads();
    const int lo = blockIdx.x * chunk, hi = min(E, lo + chunk);
    for (int e = lo + threadIdx.x; e < hi; e += 1024) {
        int s = edge[e], d = edge[E + e];
        int pos = atomicAdd(&cur[d >> 8], 1);
        g_be[pos] = ((unsigned)s << 8) | (unsigned)(d & (BN - 1));
    }
}

// One workgroup per bucket: LDS hist + scan -> rowptr, then bucket-local CSR scatter.
__global__ __launch_bounds__(BN) void k_csr(int N, int E, int nbuck) {
    const int b = blockIdx.x;
    const int nlo = b * BN;
    const int ebase = g_mat[b * B_PART] + g_bsum[(b * B_PART) >> 10];
    const int eend = (b + 1 < nbuck)
        ? (g_mat[(b + 1) * B_PART] + g_bsum[((b + 1) * B_PART) >> 10]) : E;
    __shared__ int cnt[BN];
    __shared__ int pfx[BN];
    const int tid = threadIdx.x;
    cnt[tid] = 0;
    __syncthreads();
    for (int e = ebase + tid; e < eend; e += BN)
        atomicAdd(&cnt[g_be[e] & (BN - 1)], 1);
    __syncthreads();
    int v = cnt[tid];
    pfx[tid] = v;
    __syncthreads();
    for (int off = 1; off < BN; off <<= 1) {
        int t = (tid >= off) ? pfx[tid - off] : 0;
        __syncthreads();
        pfx[tid] += t;
        __syncthreads();
    }
    int excl = pfx[tid] - v;
    int n = nlo + tid;
    if (n < N) g_rowptr[n] = ebase + excl;
    if (b == 0 && tid == 0) g_rowptr[N] = E;
    cnt[tid] = excl;  // reuse as cursor
    __syncthreads();
    for (int e = ebase + tid; e < eend; e += BN) {
        unsigned pv = g_be[e];
        int pos = atomicAdd(&cnt[pv & (BN - 1)], 1);
        g_csr[ebase + pos] = (int)(pv >> 8);
    }
}

// ---------------- degree-sort permutation (counting sort, atomic-free) ----------------
__global__ __launch_bounds__(256) void k_dcount(int N, int chunk) {
    __shared__ int h[DBIN];
    if (threadIdx.x < DBIN) h[threadIdx.x] = 0;
    __syncthreads();
    const int lo = blockIdx.x * chunk, hi = min(N, lo + chunk);
    for (int n = lo + threadIdx.x; n < hi; n += 256) {
        int deg = min(g_rowptr[n + 1] - g_rowptr[n], DBIN - 1);
        atomicAdd(&h[deg], 1);
    }
    __syncthreads();
    if (threadIdx.x < DBIN) g_dmat[threadIdx.x * PB + blockIdx.x] = h[threadIdx.x];
}

__global__ __launch_bounds__(1024) void k_dscan() {
    __shared__ int ssum[1024];
    const int tid = threadIdx.x;
    const int base = tid * 8;  // DBIN*PB = 8192 = 1024*8
    int v[8]; int s = 0;
    #pragma unroll
    for (int i = 0; i < 8; ++i) { v[i] = g_dmat[base + i]; s += v[i]; }
    ssum[tid] = s;
    __syncthreads();
    for (int off = 1; off < 1024; off <<= 1) {
        int t = (tid >= off) ? ssum[tid - off] : 0;
        __syncthreads();
        ssum[tid] += t;
        __syncthreads();
    }
    int run = ssum[tid] - s;
    #pragma unroll
    for (int i = 0; i < 8; ++i) { int d = v[i]; g_dmat[base + i] = run; run += d; }
}

__global__ __launch_bounds__(256) void k_dperm(int N, int chunk) {
    __shared__ int cur[DBIN];
    if (threadIdx.x < DBIN) cur[threadIdx.x] = g_dmat[threadIdx.x * PB + blockIdx.x];
    __syncthreads();
    const int lo = blockIdx.x * chunk, hi = min(N, lo + chunk);
    for (int n = lo + threadIdx.x; n < hi; n += 256) {
        int deg = min(g_rowptr[n + 1] - g_rowptr[n], DBIN - 1);
        int pos = atomicAdd(&cur[deg], 1);
        g_perm[pos] = n;
    }
}

// ---------------- gathers (bf16 rows, fp32 acc, 4x unrolled, degree-sorted) ----------
template <int F, int RS>
__global__ __launch_bounds__(256) void k_gather_relu(size_t oTB, size_t oR, size_t oH, int N) {
    constexpr int L = F / 8;
    int tid = blockIdx.x * 256 + threadIdx.x;
    int gid = tid / L, c = tid % L;
    if (gid >= N) return;
    const int node = g_perm[gid];
    const unsigned short* __restrict__ tb = &g_tb[oTB];
    int j = g_rowptr[node];
    const int end = g_rowptr[node + 1];
    float s0 = 0.f, s1 = 0.f, s2 = 0.f, s3 = 0.f, s4 = 0.f, s5 = 0.f, s6 = 0.f, s7 = 0.f;
    for (; j + 3 < end; j += 4) {
        int sn0 = g_csr[j], sn1 = g_csr[j + 1], sn2 = g_csr[j + 2], sn3 = g_csr[j + 3];
        const uint4 v0 = *(const uint4*)&tb[(size_t)sn0 * RS + c * 8];
        const uint4 v1 = *(const uint4*)&tb[(size_t)sn1 * RS + c * 8];
        const uint4 v2 = *(const uint4*)&tb[(size_t)sn2 * RS + c * 8];
        const uint4 v3 = *(const uint4*)&tb[(size_t)sn3 * RS + c * 8];
        s0 += bflo(v0.x) + bflo(v1.x) + bflo(v2.x) + bflo(v3.x);
        s1 += bfhi(v0.x) + bfhi(v1.x) + bfhi(v2.x) + bfhi(v3.x);
        s2 += bflo(v0.y) + bflo(v1.y) + bflo(v2.y) + bflo(v3.y);
        s3 += bfhi(v0.y) + bfhi(v1.y) + bfhi(v2.y) + bfhi(v3.y);
        s4 += bflo(v0.z) + bflo(v1.z) + bflo(v2.z) + bflo(v3.z);
        s5 += bfhi(v0.z) + bfhi(v1.z) + bfhi(v2.z) + bfhi(v3.z);
        s6 += bflo(v0.w) + bflo(v1.w) + bflo(v2.w) + bflo(v3.w);
        s7 += bfhi(v0.w) + bfhi(v1.w) + bfhi(v2.w) + bfhi(v3.w);
    }
    for (; j < end; ++j) {
        int sn = g_csr[j];
        const uint4 v = *(const uint4*)&tb[(size_t)sn * RS + c * 8];
        s0 += bflo(v.x); s1 += bfhi(v.x);
        s2 += bflo(v.y); s3 += bfhi(v.y);
        s4 += bflo(v.z); s5 += bfhi(v.z);
        s6 += bflo(v.w); s7 += bfhi(v.w);
    }
    const size_t ro = oR + (size_t)node * F + c * 8;
    const float4 ra = *(const float4*)&g_ws[ro];
    const float4 rb = *(const float4*)&g_ws[ro + 4];
    float4 oa, ob;
    oa.x = fmaxf(s0 + ra.x, 0.f); oa.y = fmaxf(s1 + ra.y, 0.f);
    oa.z = fmaxf(s2 + ra.z, 0.f); oa.w = fmaxf(s3 + ra.w, 0.f);
    ob.x = fmaxf(s4 + rb.x, 0.f); ob.y = fmaxf(s5 + rb.y, 0.f);
    ob.z = fmaxf(s6 + rb.z, 0.f); ob.w = fmaxf(s7 + rb.w, 0.f);
    const size_t ho = oH + (size_t)node * F + c * 8;
    *(float4*)&g_ws[ho] = oa;
    *(float4*)&g_ws[ho + 4] = ob;
}

__global__ __launch_bounds__(256) void k_gather_out(size_t oTB, float* __restrict__ out, int N) {
    constexpr int F = 16, L = 2;
    int tid = blockIdx.x * 256 + threadIdx.x;
    int gid = tid / L, c = tid % L;
    if (gid >= N) return;
    const int node = g_perm[gid];
    const unsigned short* __restrict__ tb = &g_tb[oTB];
    int j = g_rowptr[node];
    const int end = g_rowptr[node + 1];
    float s0 = 0.f, s1 = 0.f, s2 = 0.f, s3 = 0.f, s4 = 0.f, s5 = 0.f, s6 = 0.f, s7 = 0.f;
    for (; j + 3 < end; j += 4) {
        int sn0 = g_csr[j], sn1 = g_csr[j + 1], sn2 = g_csr[j + 2], sn3 = g_csr[j + 3];
        const uint4 v0 = *(const uint4*)&tb[(size_t)sn0 * F + c * 8];
        const uint4 v1 = *(const uint4*)&tb[(size_t)sn1 * F + c * 8];
        const uint4 v2 = *(const uint4*)&tb[(size_t)sn2 * F + c * 8];
        const uint4 v3 = *(const uint4*)&tb[(size_t)sn3 * F + c * 8];
        s0 += bflo(v0.x) + bflo(v1.x) + bflo(v2.x) + bflo(v3.x);
        s1 += bfhi(v0.x) + bfhi(v1.x) + bfhi(v2.x) + bfhi(v3.x);
        s2 += bflo(v0.y) + bflo(v1.y) + bflo(v2.y) + bflo(v3.y);
        s3 += bfhi(v0.y) + bfhi(v1.y) + bfhi(v2.y) + bfhi(v3.y);
        s4 += bflo(v0.z) + bflo(v1.z) + bflo(v2.z) + bflo(v3.z);
        s5 += bfhi(v0.z) + bfhi(v1.z) + bfhi(v2.z) + bfhi(v3.z);
        s6 += bflo(v0.w) + bflo(v1.w) + bflo(v2.w) + bflo(v3.w);
        s7 += bfhi(v0.w) + bfhi(v1.w) + bfhi(v2.w) + bfhi(v3.w);
    }
    for (; j < end; ++j) {
        int sn = g_csr[j];
        const uint4 v = *(const uint4*)&tb[(size_t)sn * F + c * 8];
        s0 += bflo(v.x); s1 += bfhi(v.x);
        s2 += bflo(v.y); s3 += bfhi(v.y);
        s4 += bflo(v.z); s5 += bfhi(v.z);
        s6 += bflo(v.w); s7 += bfhi(v.w);
    }
    float* op = &out[(size_t)node * F + c * 8];
    float4 oa = *(float4*)op;
    float4 ob = *(float4*)(op + 4);
    oa.x += s0; oa.y += s1; oa.z += s2; oa.w += s3;
    ob.x += s4; ob.y += s5; ob.z += s6; ob.w += s7;
    *(float4*)op = oa;
    *(float4*)(op + 4) = ob;
}

// ---------------- transforms (LDS-tiled, occupancy-tuned; R11-proven) ----------------
// L1: 512 thr, 128 nodes/block, sH bf16 (pad 72), 8 jg x 64 nlp, 2 nodes/thread.
#define L1_PADS 72
__global__ __launch_bounds__(512) void k_l1_transform(
        const float* __restrict__ x, const float* __restrict__ ax,
        const float* __restrict__ Wrel, const float* __restrict__ Wroot,
        const float* __restrict__ b, int N, size_t oTB1, size_t oR1) {
    __shared__ float sWrel[64 * 32];
    __shared__ float sWroot[64 * 32];
    __shared__ unsigned short sH[128 * L1_PADS];
    const int tid = threadIdx.x;
    if (tid < 512) {
        ((float4*)sWrel)[tid] = ((const float4*)Wrel)[tid];
        ((float4*)sWroot)[tid] = ((const float4*)Wroot)[tid];
    }
    const int n0 = blockIdx.x * 128;
    for (int i = tid; i < 128 * 16; i += 512) {
        int nl = i >> 4, g = i & 15, n = n0 + nl;
        float4 v = {0.f, 0.f, 0.f, 0.f};
        if (n < N) v = (g < 12) ? *(const float4*)&x[(size_t)n * 48 + g * 4]
                                : *(const float4*)&ax[(size_t)n * 16 + (g - 12) * 4];
        ushort4 hv;
        hv.x = f2bf(v.x); hv.y = f2bf(v.y); hv.z = f2bf(v.z); hv.w = f2bf(v.w);
        *(ushort4*)&sH[nl * L1_PADS + g * 4] = hv;
    }
    __syncthreads();
    const int jg = tid & 7, nlp = tid >> 3;   // 8 jg x 64 nlp
    const unsigned short* h0p = &sH[(nlp * 2 + 0) * L1_PADS];
    const unsigned short* h1p = &sH[(nlp * 2 + 1) * L1_PADS];
    float at[2][4] = {}, ar[2][4] = {};
    for (int k = 0; k < 64; ++k) {
        const float4 wr = *(const float4*)&sWrel[k * 32 + jg * 4];
        const float4 wo = *(const float4*)&sWroot[k * 32 + jg * 4];
        const float h0 = bflo(h0p[k]);
        const float h1 = bflo(h1p[k]);
        at[0][0] = fmaf(h0, wr.x, at[0][0]); at[0][1] = fmaf(h0, wr.y, at[0][1]);
        at[0][2] = fmaf(h0, wr.z, at[0][2]); at[0][3] = fmaf(h0, wr.w, at[0][3]);
        ar[0][0] = fmaf(h0, wo.x, ar[0][0]); ar[0][1] = fmaf(h0, wo.y, ar[0][1]);
        ar[0][2] = fmaf(h0, wo.z, ar[0][2]); ar[0][3] = fmaf(h0, wo.w, ar[0][3]);
        at[1][0] = fmaf(h1, wr.x, at[1][0]); at[1][1] = fmaf(h1, wr.y, at[1][1]);
        at[1][2] = fmaf(h1, wr.z, at[1][2]); at[1][3] = fmaf(h1, wr.w, at[1][3]);
        ar[1][0] = fmaf(h1, wo.x, ar[1][0]); ar[1][1] = fmaf(h1, wo.y, ar[1][1]);
        ar[1][2] = fmaf(h1, wo.z, ar[1][2]); ar[1][3] = fmaf(h1, wo.w, ar[1][3]);
    }
    const float4 bv = *(const float4*)&b[jg * 4];
    #pragma unroll
    for (int m = 0; m < 2; ++m) {
        int n = n0 + nlp * 2 + m;
        if (n < N) {
            ushort4 tv;
            tv.x = f2bf(at[m][0]); tv.y = f2bf(at[m][1]);
            tv.z = f2bf(at[m][2]); tv.w = f2bf(at[m][3]);
            *(ushort4*)&g_tb[oTB1 + (size_t)n * 32 + jg * 4] = tv;
            float4 rv;
            rv.x = ar[m][0] + bv.x; rv.y = ar[m][1] + bv.y;
            rv.z = ar[m][2] + bv.z; rv.w = ar[m][3] + bv.w;
            *(float4*)&g_ws[oR1 + (size_t)n * 32 + jg * 4] = rv;
        }
    }
}

// L2: 384 thr, 64 nodes/block, fp32 sH (pad 49), 12 jg x 32 nlp, 2 nodes/thread.
// t2 rows padded to 64 shorts (128 B) for single-line gathers.
#define L2_PAD 49
__global__ __launch_bounds__(384) void k_l2_transform(
        const float* __restrict__ lf,
        const float* __restrict__ Wrel, const float* __restrict__ Wroot,
        const float* __restrict__ b, int N,
        size_t oH1, size_t oTB2, size_t oR2) {
    __shared__ float sWrel[48 * 48];
    __shared__ float sWroot[48 * 48];
    __shared__ float sH[64 * L2_PAD];
    const int tid = threadIdx.x;
    for (int i = tid; i < 576; i += 384) {
        ((float4*)sWrel)[i] = ((const float4*)Wrel)[i];
        ((float4*)sWroot)[i] = ((const float4*)Wroot)[i];
    }
    const int n0 = blockIdx.x * 64;
    for (int i = tid; i < 64 * 48; i += 384) {
        int nl = i / 48, k = i % 48, n = n0 + nl;
        float v = 0.f;
        if (n < N) v = (k < 32) ? g_ws[oH1 + (size_t)n * 32 + k]
                                : lf[(size_t)n * 16 + (k - 32)];
        sH[nl * L2_PAD + k] = v;
    }
    __syncthreads();
    const int jg = tid % 12, nlp = tid / 12;  // 12 jg x 32 nlp
    const float* h0p = &sH[(nlp * 2 + 0) * L2_PAD];
    const float* h1p = &sH[(nlp * 2 + 1) * L2_PAD];
    float at[2][4] = {}, ar[2][4] = {};
    for (int k = 0; k < 48; ++k) {
        const float4 wr = *(const float4*)&sWrel[k * 48 + jg * 4];
        const float4 wo = *(const float4*)&sWroot[k * 48 + jg * 4];
        const float h0 = h0p[k];
        const float h1 = h1p[k];
        at[0][0] = fmaf(h0, wr.x, at[0][0]); at[0][1] = fmaf(h0, wr.y, at[0][1]);
        at[0][2] = fmaf(h0, wr.z, at[0][2]); at[0][3] = fmaf(h0, wr.w, at[0][3]);
        ar[0][0] = fmaf(h0, wo.x, ar[0][0]); ar[0][1] = fmaf(h0, wo.y, ar[0][1]);
        ar[0][2] = fmaf(h0, wo.z, ar[0][2]); ar[0][3] = fmaf(h0, wo.w, ar[0][3]);
        at[1][0] = fmaf(h1, wr.x, at[1][0]); at[1][1] = fmaf(h1, wr.y, at[1][1]);
        at[1][2] = fmaf(h1, wr.z, at[1][2]); at[1][3] = fmaf(h1, wr.w, at[1][3]);
        ar[1][0] = fmaf(h1, wo.x, ar[1][0]); ar[1][1] = fmaf(h1, wo.y, ar[1][1]);
        ar[1][2] = fmaf(h1, wo.z, ar[1][2]); ar[1][3] = fmaf(h1, wo.w, ar[1][3]);
    }
    const float4 bv = *(const float4*)&b[jg * 4];
    #pragma unroll
    for (int m = 0; m < 2; ++m) {
        int n = n0 + nlp * 2 + m;
        if (n < N) {
            ushort4 tv;
            tv.x = f2bf(at[m][0]); tv.y = f2bf(at[m][1]);
            tv.z = f2bf(at[m][2]); tv.w = f2bf(at[m][3]);
            *(ushort4*)&g_tb[oTB2 + (size_t)n * 64 + jg * 4] = tv;   // stride 64 (padded)
            float4 rv;
            rv.x = ar[m][0] + bv.x; rv.y = ar[m][1] + bv.y;
            rv.z = ar[m][2] + bv.z; rv.w = ar[m][3] + bv.w;
            *(float4*)&g_ws[oR2 + (size_t)n * 48 + jg * 4] = rv;
        }
    }
}

// L3: 256 thr, 128 nodes/block, fp32 sH (pad 49), 4 jg x 64 nlp, 2 nodes/thread.
#define L3_PAD 49
__global__ __launch_bounds__(256) void k_l3_transform(
        const float* __restrict__ ax,
        const float* __restrict__ Wrel, const float* __restrict__ Wroot,
        const float* __restrict__ b, int N,
        size_t oH2, size_t oTB3, float* __restrict__ out) {
    __shared__ float sWrel[48 * 16];
    __shared__ float sWroot[48 * 16];
    __shared__ float sH[128 * L3_PAD];
    const int tid = threadIdx.x;
    if (tid < 192) {
        ((float4*)sWrel)[tid] = ((const float4*)Wrel)[tid];
        ((float4*)sWroot)[tid] = ((const float4*)Wroot)[tid];
    }
    const int n0 = blockIdx.x * 128;
    for (int i = tid; i < 128 * 48; i += 256) {
        int nl = i / 48, k = i % 48, n = n0 + nl;
        sH[nl * L3_PAD + k] = (n < N) ? g_ws[oH2 + (size_t)n * 48 + k] : 0.f;
    }
    __syncthreads();
    const int jg = tid & 3, nlp = tid >> 2;   // 4 jg x 64 nlp
    const float* h0p = &sH[(nlp * 2 + 0) * L3_PAD];
    const float* h1p = &sH[(nlp * 2 + 1) * L3_PAD];
    float at[2][4] = {}, ar[2][4] = {};
    for (int k = 0; k < 48; ++k) {
        const float4 wr = *(const float4*)&sWrel[k * 16 + jg * 4];
        const float4 wo = *(const float4*)&sWroot[k * 16 + jg * 4];
        const float h0 = h0p[k];
        const float h1 = h1p[k];
        at[0][0] = fmaf(h0, wr.x, at[0][0]); at[0][1] = fmaf(h0, wr.y, at[0][1]);
        at[0][2] = fmaf(h0, wr.z, at[0][2]); at[0][3] = fmaf(h0, wr.w, at[0][3]);
        ar[0][0] = fmaf(h0, wo.x, ar[0][0]); ar[0][1] = fmaf(h0, wo.y, ar[0][1]);
        ar[0][2] = fmaf(h0, wo.z, ar[0][2]); ar[0][3] = fmaf(h0, wo.w, ar[0][3]);
        at[1][0] = fmaf(h1, wr.x, at[1][0]); at[1][1] = fmaf(h1, wr.y, at[1][1]);
        at[1][2] = fmaf(h1, wr.z, at[1][2]); at[1][3] = fmaf(h1, wr.w, at[1][3]);
        ar[1][0] = fmaf(h1, wo.x, ar[1][0]); ar[1][1] = fmaf(h1, wo.y, ar[1][1]);
        ar[1][2] = fmaf(h1, wo.z, ar[1][2]); ar[1][3] = fmaf(h1, wo.w, ar[1][3]);
    }
    const float4 bv = *(const float4*)&b[jg * 4];
    #pragma unroll
    for (int m = 0; m < 2; ++m) {
        int n = n0 + nlp * 2 + m;
        if (n < N) {
            ushort4 tv;
            tv.x = f2bf(at[m][0]); tv.y = f2bf(at[m][1]);
            tv.z = f2bf(at[m][2]); tv.w = f2bf(at[m][3]);
            *(ushort4*)&g_tb[oTB3 + (size_t)n * 16 + jg * 4] = tv;
            const float4 av = *(const float4*)&ax[(size_t)n * 16 + jg * 4];
            float4 rv;
            rv.x = ar[m][0] + bv.x + av.x; rv.y = ar[m][1] + bv.y + av.y;
            rv.z = ar[m][2] + bv.z + av.z; rv.w = ar[m][3] + bv.w + av.w;
            *(float4*)&out[(size_t)n * 16 + jg * 4] = rv;
        }
    }
}

extern "C" void kernel_launch(void* const* d_in, const int* in_sizes, int n_in,
                              void* d_out, int out_size, void* d_ws, size_t ws_size,
                              hipStream_t stream) {
    const float* x     = (const float*)d_in[0];
    const int*   edge  = (const int*)d_in[1];
    const float* ax    = (const float*)d_in[2];
    const float* lf    = (const float*)d_in[3];
    const float* W1rel = (const float*)d_in[4];
    const float* b1    = (const float*)d_in[5];
    const float* W1root= (const float*)d_in[6];
    const float* W2rel = (const float*)d_in[7];
    const float* b2    = (const float*)d_in[8];
    const float* W2root= (const float*)d_in[9];
    const float* W3rel = (const float*)d_in[10];
    const float* b3    = (const float*)d_in[11];
    const float* W3root= (const float*)d_in[12];
    float* out = (float*)d_out;

    const int N = in_sizes[0] / 48;
    const int E = in_sizes[1] / 2;
    const int nbuck = (N + BN - 1) / BN;
    const int chunk = (E + B_PART - 1) / B_PART;
    const int M = nbuck * B_PART;
    const int nb = (M + SCAN_CHUNK - 1) / SCAN_CHUNK;
    const int pchunk = (N + PB - 1) / PB;

    // fp32 tables
    const size_t oR1 = 0;
    const size_t oH1 = (size_t)N * 32;
    const size_t oR2 = (size_t)N * 64;
    const size_t oH2 = (size_t)N * 112;
    // bf16 t-tables (t2 rows padded to 64 shorts)
    const size_t oTB1 = 0;
    const size_t oTB2 = (size_t)N * 32;
    const size_t oTB3 = (size_t)N * 96;

    // CSR build (radix partition, no global atomics)
    k_bcount<<<B_PART, 1024, 0, stream>>>(edge, E, nbuck, chunk);
    k_scan_local<<<nb, 256, 0, stream>>>(M);
    k_scan_bsums<<<1, 1024, 0, stream>>>(nb);
    k_bpart<<<B_PART, 1024, 0, stream>>>(edge, E, nbuck, chunk);
    k_csr<<<nbuck, BN, 0, stream>>>(N, E, nbuck);
    // Degree-sorted permutation (counting sort)
    k_dcount<<<PB, 256, 0, stream>>>(N, pchunk);
    k_dscan<<<1, 1024, 0, stream>>>();
    k_dperm<<<PB, 256, 0, stream>>>(N, pchunk);

    // Layer 1
    k_l1_transform<<<(N + 127) / 128, 512, 0, stream>>>(x, ax, W1rel, W1root, b1, N, oTB1, oR1);
    k_gather_relu<32, 32><<<(unsigned)(((size_t)N * 4 + 255) / 256), 256, 0, stream>>>(oTB1, oR1, oH1, N);
    // Layer 2
    k_l2_transform<<<(N + 63) / 64, 384, 0, stream>>>(lf, W2rel, W2root, b2, N, oH1, oTB2, oR2);
    k_gather_relu<48, 64><<<(unsigned)(((size_t)N * 6 + 255) / 256), 256, 0, stream>>>(oTB2, oR2, oH2, N);
    // Layer 3
    k_l3_transform<<<(N + 127) / 128, 256, 0, stream>>>(ax, W3rel, W3root, b3, N, oH2, oTB3, out);
    k_gather_out<<<(unsigned)(((size_t)N * 2 + 255) / 256), 256, 0, stream>>>(oTB3, out, N);
}

// Round 14
// 290.733 us; speedup vs baseline: 1.1541x; 1.1541x over previous
//
#include <hip/hip_runtime.h>

#define NODES_MAX 100000
#define EDGES_MAX 1600000
#define BN 256                                   // nodes per bucket (pow2)
#define NBUCK ((NODES_MAX + BN - 1) / BN)        // 391
#define B_PART 256                               // partition blocks (fixed)
#define SCAN_CHUNK 1024

// fp32 scratch (r/h tables): r1:0(32) h1:N*32(32) r2:N*64(48) h2:N*112(48)
__device__ float g_ws[(size_t)NODES_MAX * 160];
// bf16 t-tables: t1:0 (32/node) | t2:N*32 (64/node, 48 used: 128B-aligned rows) | t3:N*96 (16/node)
__device__ unsigned short g_tb[(size_t)NODES_MAX * 112];
__device__ int g_rowptr[NODES_MAX + 1];
__device__ int g_csr[EDGES_MAX];            // src ids grouped by dst
__device__ unsigned g_be[EDGES_MAX];        // bucket-ordered packed (src<<8)|local_dst
__device__ int g_mat[NBUCK * B_PART];       // per-(bucket,block) counts -> local-excl prefixes
__device__ int g_bsum[(NBUCK * B_PART + SCAN_CHUNK - 1) / SCAN_CHUNK + 1];

__device__ __forceinline__ unsigned short f2bf(float f) {
    union { float f; unsigned u; } c; c.f = f;
    unsigned r = (c.u + 0x7FFFu + ((c.u >> 16) & 1u)) >> 16;
    return (unsigned short)r;
}
__device__ __forceinline__ float bflo(unsigned u) {
    union { unsigned u; float f; } c; c.u = u << 16; return c.f;
}
__device__ __forceinline__ float bfhi(unsigned u) {
    union { unsigned u; float f; } c; c.u = u & 0xFFFF0000u; return c.f;
}

// ---------------- CSR build (radix partition, no global atomics) ----------------
__global__ __launch_bounds__(1024) void k_bcount(const int* __restrict__ edge, int E,
                                                 int nbuck, int chunk) {
    __shared__ int h[NBUCK];
    for (int i = threadIdx.x; i < nbuck; i += 1024) h[i] = 0;
    __syncthreads();
    const int lo = blockIdx.x * chunk, hi = min(E, lo + chunk);
    for (int e = lo + threadIdx.x; e < hi; e += 1024)
        atomicAdd(&h[edge[E + e] >> 8], 1);
    __syncthreads();
    for (int k = threadIdx.x; k < nbuck; k += 1024)
        g_mat[k * B_PART + blockIdx.x] = h[k];
}

__global__ __launch_bounds__(256) void k_scan_local(int M) {
    __shared__ int ssum[256];
    const int tid = threadIdx.x;
    const int base = blockIdx.x * SCAN_CHUNK + tid * 4;
    int v0 = (base + 0 < M) ? g_mat[base + 0] : 0;
    int v1 = (base + 1 < M) ? g_mat[base + 1] : 0;
    int v2 = (base + 2 < M) ? g_mat[base + 2] : 0;
    int v3 = (base + 3 < M) ? g_mat[base + 3] : 0;
    int s = v0 + v1 + v2 + v3;
    ssum[tid] = s;
    __syncthreads();
    for (int off = 1; off < 256; off <<= 1) {
        int v = (tid >= off) ? ssum[tid - off] : 0;
        __syncthreads();
        ssum[tid] += v;
        __syncthreads();
    }
    int run = ssum[tid] - s;
    if (base + 0 < M) g_mat[base + 0] = run;
    run += v0;
    if (base + 1 < M) g_mat[base + 1] = run;
    run += v1;
    if (base + 2 < M) g_mat[base + 2] = run;
    run += v2;
    if (base + 3 < M) g_mat[base + 3] = run;
    if (tid == 255) g_bsum[blockIdx.x] = ssum[255];
}

__global__ __launch_bounds__(1024) void k_scan_bsums(int nb) {
    __shared__ int ssum[1024];
    const int tid = threadIdx.x;
    int s = (tid < nb) ? g_bsum[tid] : 0;
    ssum[tid] = s;
    __syncthreads();
    for (int off = 1; off < 1024; off <<= 1) {
        int v = (tid >= off) ? ssum[tid - off] : 0;
        __syncthreads();
        ssum[tid] += v;
        __syncthreads();
    }
    if (tid < nb) g_bsum[tid] = ssum[tid] - s;
}

// Phase 3: re-read chunk, rank via LDS cursors (global offsets folded in here).
__global__ __launch_bounds__(1024) void k_bpart(const int* __restrict__ edge, int E,
                                                int nbuck, int chunk) {
    __shared__ int cur[NBUCK];
    for (int k = threadIdx.x; k < nbuck; k += 1024) {
        int idx = k * B_PART + blockIdx.x;
        cur[k] = g_mat[idx] + g_bsum[idx >> 10];
    }
    __syncthreads();
    const int lo = blockIdx.x * chunk, hi = min(E, lo + chunk);
    for (int e = lo + threadIdx.x; e < hi; e += 1024) {
        int s = edge[e], d = edge[E + e];
        int pos = atomicAdd(&cur[d >> 8], 1);
        g_be[pos] = ((unsigned)s << 8) | (unsigned)(d & (BN - 1));
    }
}

// One workgroup per bucket: LDS hist + scan -> rowptr, then bucket-local CSR scatter.
__global__ __launch_bounds__(BN) void k_csr(int N, int E, int nbuck) {
    const int b = blockIdx.x;
    const int nlo = b * BN;
    const int ebase = g_mat[b * B_PART] + g_bsum[(b * B_PART) >> 10];
    const int eend = (b + 1 < nbuck)
        ? (g_mat[(b + 1) * B_PART] + g_bsum[((b + 1) * B_PART) >> 10]) : E;
    __shared__ int cnt[BN];
    __shared__ int pfx[BN];
    const int tid = threadIdx.x;
    cnt[tid] = 0;
    __syncthreads();
    for (int e = ebase + tid; e < eend; e += BN)
        atomicAdd(&cnt[g_be[e] & (BN - 1)], 1);
    __syncthreads();
    int v = cnt[tid];
    pfx[tid] = v;
    __syncthreads();
    for (int off = 1; off < BN; off <<= 1) {
        int t = (tid >= off) ? pfx[tid - off] : 0;
        __syncthreads();
        pfx[tid] += t;
        __syncthreads();
    }
    int excl = pfx[tid] - v;
    int n = nlo + tid;
    if (n < N) g_rowptr[n] = ebase + excl;
    if (b == 0 && tid == 0) g_rowptr[N] = E;
    cnt[tid] = excl;  // reuse as cursor
    __syncthreads();
    for (int e = ebase + tid; e < eend; e += BN) {
        unsigned pv = g_be[e];
        int pos = atomicAdd(&cnt[pv & (BN - 1)], 1);
        g_csr[ebase + pos] = (int)(pv >> 8);
    }
}

// ---------------- gathers (bf16 rows, fp32 accumulate) ----------------
// F = features summed (8 per lane), RS = row stride in shorts, U = max unroll (4 or 8).
template <int F, int RS, int U>
__global__ __launch_bounds__(256) void k_gather_relu(size_t oTB, size_t oR, size_t oH, int N) {
    constexpr int L = F / 8;
    int tid = blockIdx.x * 256 + threadIdx.x;
    int node = tid / L, c = tid % L;
    if (node >= N) return;
    const unsigned short* __restrict__ tb = &g_tb[oTB];
    int j = g_rowptr[node];
    const int end = g_rowptr[node + 1];
    float s0 = 0.f, s1 = 0.f, s2 = 0.f, s3 = 0.f, s4 = 0.f, s5 = 0.f, s6 = 0.f, s7 = 0.f;
    if (U >= 8) {
        for (; j + 7 < end; j += 8) {
            uint4 v[8];
            #pragma unroll
            for (int u = 0; u < 8; ++u)
                v[u] = *(const uint4*)&tb[(size_t)g_csr[j + u] * RS + c * 8];
            #pragma unroll
            for (int u = 0; u < 8; ++u) {
                s0 += bflo(v[u].x); s1 += bfhi(v[u].x);
                s2 += bflo(v[u].y); s3 += bfhi(v[u].y);
                s4 += bflo(v[u].z); s5 += bfhi(v[u].z);
                s6 += bflo(v[u].w); s7 += bfhi(v[u].w);
            }
        }
    }
    for (; j + 3 < end; j += 4) {
        int sn0 = g_csr[j], sn1 = g_csr[j + 1], sn2 = g_csr[j + 2], sn3 = g_csr[j + 3];
        const uint4 v0 = *(const uint4*)&tb[(size_t)sn0 * RS + c * 8];
        const uint4 v1 = *(const uint4*)&tb[(size_t)sn1 * RS + c * 8];
        const uint4 v2 = *(const uint4*)&tb[(size_t)sn2 * RS + c * 8];
        const uint4 v3 = *(const uint4*)&tb[(size_t)sn3 * RS + c * 8];
        s0 += bflo(v0.x) + bflo(v1.x) + bflo(v2.x) + bflo(v3.x);
        s1 += bfhi(v0.x) + bfhi(v1.x) + bfhi(v2.x) + bfhi(v3.x);
        s2 += bflo(v0.y) + bflo(v1.y) + bflo(v2.y) + bflo(v3.y);
        s3 += bfhi(v0.y) + bfhi(v1.y) + bfhi(v2.y) + bfhi(v3.y);
        s4 += bflo(v0.z) + bflo(v1.z) + bflo(v2.z) + bflo(v3.z);
        s5 += bfhi(v0.z) + bfhi(v1.z) + bfhi(v2.z) + bfhi(v3.z);
        s6 += bflo(v0.w) + bflo(v1.w) + bflo(v2.w) + bflo(v3.w);
        s7 += bfhi(v0.w) + bfhi(v1.w) + bfhi(v2.w) + bfhi(v3.w);
    }
    for (; j < end; ++j) {
        int sn = g_csr[j];
        const uint4 v = *(const uint4*)&tb[(size_t)sn * RS + c * 8];
        s0 += bflo(v.x); s1 += bfhi(v.x);
        s2 += bflo(v.y); s3 += bfhi(v.y);
        s4 += bflo(v.z); s5 += bfhi(v.z);
        s6 += bflo(v.w); s7 += bfhi(v.w);
    }
    const size_t ro = oR + (size_t)node * F + c * 8;
    const float4 ra = *(const float4*)&g_ws[ro];
    const float4 rb = *(const float4*)&g_ws[ro + 4];
    float4 oa, ob;
    oa.x = fmaxf(s0 + ra.x, 0.f); oa.y = fmaxf(s1 + ra.y, 0.f);
    oa.z = fmaxf(s2 + ra.z, 0.f); oa.w = fmaxf(s3 + ra.w, 0.f);
    ob.x = fmaxf(s4 + rb.x, 0.f); ob.y = fmaxf(s5 + rb.y, 0.f);
    ob.z = fmaxf(s6 + rb.z, 0.f); ob.w = fmaxf(s7 + rb.w, 0.f);
    const size_t ho = oH + (size_t)node * F + c * 8;
    *(float4*)&g_ws[ho] = oa;
    *(float4*)&g_ws[ho + 4] = ob;
}

__global__ __launch_bounds__(256) void k_gather_out(size_t oTB, float* __restrict__ out, int N) {
    constexpr int F = 16, L = 2;
    int tid = blockIdx.x * 256 + threadIdx.x;
    int node = tid / L, c = tid % L;
    if (node >= N) return;
    const unsigned short* __restrict__ tb = &g_tb[oTB];
    int j = g_rowptr[node];
    const int end = g_rowptr[node + 1];
    float s0 = 0.f, s1 = 0.f, s2 = 0.f, s3 = 0.f, s4 = 0.f, s5 = 0.f, s6 = 0.f, s7 = 0.f;
    for (; j + 3 < end; j += 4) {
        int sn0 = g_csr[j], sn1 = g_csr[j + 1], sn2 = g_csr[j + 2], sn3 = g_csr[j + 3];
        const uint4 v0 = *(const uint4*)&tb[(size_t)sn0 * F + c * 8];
        const uint4 v1 = *(const uint4*)&tb[(size_t)sn1 * F + c * 8];
        const uint4 v2 = *(const uint4*)&tb[(size_t)sn2 * F + c * 8];
        const uint4 v3 = *(const uint4*)&tb[(size_t)sn3 * F + c * 8];
        s0 += bflo(v0.x) + bflo(v1.x) + bflo(v2.x) + bflo(v3.x);
        s1 += bfhi(v0.x) + bfhi(v1.x) + bfhi(v2.x) + bfhi(v3.x);
        s2 += bflo(v0.y) + bflo(v1.y) + bflo(v2.y) + bflo(v3.y);
        s3 += bfhi(v0.y) + bfhi(v1.y) + bfhi(v2.y) + bfhi(v3.y);
        s4 += bflo(v0.z) + bflo(v1.z) + bflo(v2.z) + bflo(v3.z);
        s5 += bfhi(v0.z) + bfhi(v1.z) + bfhi(v2.z) + bfhi(v3.z);
        s6 += bflo(v0.w) + bflo(v1.w) + bflo(v2.w) + bflo(v3.w);
        s7 += bfhi(v0.w) + bfhi(v1.w) + bfhi(v2.w) + bfhi(v3.w);
    }
    for (; j < end; ++j) {
        int sn = g_csr[j];
        const uint4 v = *(const uint4*)&tb[(size_t)sn * F + c * 8];
        s0 += bflo(v.x); s1 += bfhi(v.x);
        s2 += bflo(v.y); s3 += bfhi(v.y);
        s4 += bflo(v.z); s5 += bfhi(v.z);
        s6 += bflo(v.w); s7 += bfhi(v.w);
    }
    float* op = &out[(size_t)node * F + c * 8];
    float4 oa = *(float4*)op;
    float4 ob = *(float4*)(op + 4);
    oa.x += s0; oa.y += s1; oa.z += s2; oa.w += s3;
    ob.x += s4; ob.y += s5; ob.z += s6; ob.w += s7;
    *(float4*)op = oa;
    *(float4*)(op + 4) = ob;
}

// ---------------- transforms (LDS-tiled, occupancy-tuned; R11-proven) ----------------
// L1: 512 thr, 128 nodes/block, sH bf16 (pad 72), 8 jg x 64 nlp, 2 nodes/thread.
#define L1_PADS 72
__global__ __launch_bounds__(512) void k_l1_transform(
        const float* __restrict__ x, const float* __restrict__ ax,
        const float* __restrict__ Wrel, const float* __restrict__ Wroot,
        const float* __restrict__ b, int N, size_t oTB1, size_t oR1) {
    __shared__ float sWrel[64 * 32];
    __shared__ float sWroot[64 * 32];
    __shared__ unsigned short sH[128 * L1_PADS];
    const int tid = threadIdx.x;
    if (tid < 512) {
        ((float4*)sWrel)[tid] = ((const float4*)Wrel)[tid];
        ((float4*)sWroot)[tid] = ((const float4*)Wroot)[tid];
    }
    const int n0 = blockIdx.x * 128;
    for (int i = tid; i < 128 * 16; i += 512) {
        int nl = i >> 4, g = i & 15, n = n0 + nl;
        float4 v = {0.f, 0.f, 0.f, 0.f};
        if (n < N) v = (g < 12) ? *(const float4*)&x[(size_t)n * 48 + g * 4]
                                : *(const float4*)&ax[(size_t)n * 16 + (g - 12) * 4];
        ushort4 hv;
        hv.x = f2bf(v.x); hv.y = f2bf(v.y); hv.z = f2bf(v.z); hv.w = f2bf(v.w);
        *(ushort4*)&sH[nl * L1_PADS + g * 4] = hv;
    }
    __syncthreads();
    const int jg = tid & 7, nlp = tid >> 3;   // 8 jg x 64 nlp
    const unsigned short* h0p = &sH[(nlp * 2 + 0) * L1_PADS];
    const unsigned short* h1p = &sH[(nlp * 2 + 1) * L1_PADS];
    float at[2][4] = {}, ar[2][4] = {};
    for (int k = 0; k < 64; ++k) {
        const float4 wr = *(const float4*)&sWrel[k * 32 + jg * 4];
        const float4 wo = *(const float4*)&sWroot[k * 32 + jg * 4];
        const float h0 = bflo(h0p[k]);
        const float h1 = bflo(h1p[k]);
        at[0][0] = fmaf(h0, wr.x, at[0][0]); at[0][1] = fmaf(h0, wr.y, at[0][1]);
        at[0][2] = fmaf(h0, wr.z, at[0][2]); at[0][3] = fmaf(h0, wr.w, at[0][3]);
        ar[0][0] = fmaf(h0, wo.x, ar[0][0]); ar[0][1] = fmaf(h0, wo.y, ar[0][1]);
        ar[0][2] = fmaf(h0, wo.z, ar[0][2]); ar[0][3] = fmaf(h0, wo.w, ar[0][3]);
        at[1][0] = fmaf(h1, wr.x, at[1][0]); at[1][1] = fmaf(h1, wr.y, at[1][1]);
        at[1][2] = fmaf(h1, wr.z, at[1][2]); at[1][3] = fmaf(h1, wr.w, at[1][3]);
        ar[1][0] = fmaf(h1, wo.x, ar[1][0]); ar[1][1] = fmaf(h1, wo.y, ar[1][1]);
        ar[1][2] = fmaf(h1, wo.z, ar[1][2]); ar[1][3] = fmaf(h1, wo.w, ar[1][3]);
    }
    const float4 bv = *(const float4*)&b[jg * 4];
    #pragma unroll
    for (int m = 0; m < 2; ++m) {
        int n = n0 + nlp * 2 + m;
        if (n < N) {
            ushort4 tv;
            tv.x = f2bf(at[m][0]); tv.y = f2bf(at[m][1]);
            tv.z = f2bf(at[m][2]); tv.w = f2bf(at[m][3]);
            *(ushort4*)&g_tb[oTB1 + (size_t)n * 32 + jg * 4] = tv;
            float4 rv;
            rv.x = ar[m][0] + bv.x; rv.y = ar[m][1] + bv.y;
            rv.z = ar[m][2] + bv.z; rv.w = ar[m][3] + bv.w;
            *(float4*)&g_ws[oR1 + (size_t)n * 32 + jg * 4] = rv;
        }
    }
}

// L2: 384 thr, 64 nodes/block, fp32 sH (pad 49), 12 jg x 32 nlp, 2 nodes/thread.
// t2 rows padded to 64 shorts (128 B) for single-line gathers.
#define L2_PAD 49
__global__ __launch_bounds__(384) void k_l2_transform(
        const float* __restrict__ lf,
        const float* __restrict__ Wrel, const float* __restrict__ Wroot,
        const float* __restrict__ b, int N,
        size_t oH1, size_t oTB2, size_t oR2) {
    __shared__ float sWrel[48 * 48];
    __shared__ float sWroot[48 * 48];
    __shared__ float sH[64 * L2_PAD];
    const int tid = threadIdx.x;
    for (int i = tid; i < 576; i += 384) {
        ((float4*)sWrel)[i] = ((const float4*)Wrel)[i];
        ((float4*)sWroot)[i] = ((const float4*)Wroot)[i];
    }
    const int n0 = blockIdx.x * 64;
    for (int i = tid; i < 64 * 48; i += 384) {
        int nl = i / 48, k = i % 48, n = n0 + nl;
        float v = 0.f;
        if (n < N) v = (k < 32) ? g_ws[oH1 + (size_t)n * 32 + k]
                                : lf[(size_t)n * 16 + (k - 32)];
        sH[nl * L2_PAD + k] = v;
    }
    __syncthreads();
    const int jg = tid % 12, nlp = tid / 12;  // 12 jg x 32 nlp
    const float* h0p = &sH[(nlp * 2 + 0) * L2_PAD];
    const float* h1p = &sH[(nlp * 2 + 1) * L2_PAD];
    float at[2][4] = {}, ar[2][4] = {};
    for (int k = 0; k < 48; ++k) {
        const float4 wr = *(const float4*)&sWrel[k * 48 + jg * 4];
        const float4 wo = *(const float4*)&sWroot[k * 48 + jg * 4];
        const float h0 = h0p[k];
        const float h1 = h1p[k];
        at[0][0] = fmaf(h0, wr.x, at[0][0]); at[0][1] = fmaf(h0, wr.y, at[0][1]);
        at[0][2] = fmaf(h0, wr.z, at[0][2]); at[0][3] = fmaf(h0, wr.w, at[0][3]);
        ar[0][0] = fmaf(h0, wo.x, ar[0][0]); ar[0][1] = fmaf(h0, wo.y, ar[0][1]);
        ar[0][2] = fmaf(h0, wo.z, ar[0][2]); ar[0][3] = fmaf(h0, wo.w, ar[0][3]);
        at[1][0] = fmaf(h1, wr.x, at[1][0]); at[1][1] = fmaf(h1, wr.y, at[1][1]);
        at[1][2] = fmaf(h1, wr.z, at[1][2]); at[1][3] = fmaf(h1, wr.w, at[1][3]);
        ar[1][0] = fmaf(h1, wo.x, ar[1][0]); ar[1][1] = fmaf(h1, wo.y, ar[1][1]);
        ar[1][2] = fmaf(h1, wo.z, ar[1][2]); ar[1][3] = fmaf(h1, wo.w, ar[1][3]);
    }
    const float4 bv = *(const float4*)&b[jg * 4];
    #pragma unroll
    for (int m = 0; m < 2; ++m) {
        int n = n0 + nlp * 2 + m;
        if (n < N) {
            ushort4 tv;
            tv.x = f2bf(at[m][0]); tv.y = f2bf(at[m][1]);
            tv.z = f2bf(at[m][2]); tv.w = f2bf(at[m][3]);
            *(ushort4*)&g_tb[oTB2 + (size_t)n * 64 + jg * 4] = tv;   // stride 64 (padded)
            float4 rv;
            rv.x = ar[m][0] + bv.x; rv.y = ar[m][1] + bv.y;
            rv.z = ar[m][2] + bv.z; rv.w = ar[m][3] + bv.w;
            *(float4*)&g_ws[oR2 + (size_t)n * 48 + jg * 4] = rv;
        }
    }
}

// L3: 256 thr, 128 nodes/block, fp32 sH (pad 49), 4 jg x 64 nlp, 2 nodes/thread.
#define L3_PAD 49
__global__ __launch_bounds__(256) void k_l3_transform(
        const float* __restrict__ ax,
        const float* __restrict__ Wrel, const float* __restrict__ Wroot,
        const float* __restrict__ b, int N,
        size_t oH2, size_t oTB3, float* __restrict__ out) {
    __shared__ float sWrel[48 * 16];
    __shared__ float sWroot[48 * 16];
    __shared__ float sH[128 * L3_PAD];
    const int tid = threadIdx.x;
    if (tid < 192) {
        ((float4*)sWrel)[tid] = ((const float4*)Wrel)[tid];
        ((float4*)sWroot)[tid] = ((const float4*)Wroot)[tid];
    }
    const int n0 = blockIdx.x * 128;
    for (int i = tid; i < 128 * 48; i += 256) {
        int nl = i / 48, k = i % 48, n = n0 + nl;
        sH[nl * L3_PAD + k] = (n < N) ? g_ws[oH2 + (size_t)n * 48 + k] : 0.f;
    }
    __syncthreads();
    const int jg = tid & 3, nlp = tid >> 2;   // 4 jg x 64 nlp
    const float* h0p = &sH[(nlp * 2 + 0) * L3_PAD];
    const float* h1p = &sH[(nlp * 2 + 1) * L3_PAD];
    float at[2][4] = {}, ar[2][4] = {};
    for (int k = 0; k < 48; ++k) {
        const float4 wr = *(const float4*)&sWrel[k * 16 + jg * 4];
        const float4 wo = *(const float4*)&sWroot[k * 16 + jg * 4];
        const float h0 = h0p[k];
        const float h1 = h1p[k];
        at[0][0] = fmaf(h0, wr.x, at[0][0]); at[0][1] = fmaf(h0, wr.y, at[0][1]);
        at[0][2] = fmaf(h0, wr.z, at[0][2]); at[0][3] = fmaf(h0, wr.w, at[0][3]);
        ar[0][0] = fmaf(h0, wo.x, ar[0][0]); ar[0][1] = fmaf(h0, wo.y, ar[0][1]);
        ar[0][2] = fmaf(h0, wo.z, ar[0][2]); ar[0][3] = fmaf(h0, wo.w, ar[0][3]);
        at[1][0] = fmaf(h1, wr.x, at[1][0]); at[1][1] = fmaf(h1, wr.y, at[1][1]);
        at[1][2] = fmaf(h1, wr.z, at[1][2]); at[1][3] = fmaf(h1, wr.w, at[1][3]);
        ar[1][0] = fmaf(h1, wo.x, ar[1][0]); ar[1][1] = fmaf(h1, wo.y, ar[1][1]);
        ar[1][2] = fmaf(h1, wo.z, ar[1][2]); ar[1][3] = fmaf(h1, wo.w, ar[1][3]);
    }
    const float4 bv = *(const float4*)&b[jg * 4];
    #pragma unroll
    for (int m = 0; m < 2; ++m) {
        int n = n0 + nlp * 2 + m;
        if (n < N) {
            ushort4 tv;
            tv.x = f2bf(at[m][0]); tv.y = f2bf(at[m][1]);
            tv.z = f2bf(at[m][2]); tv.w = f2bf(at[m][3]);
            *(ushort4*)&g_tb[oTB3 + (size_t)n * 16 + jg * 4] = tv;
            const float4 av = *(const float4*)&ax[(size_t)n * 16 + jg * 4];
            float4 rv;
            rv.x = ar[m][0] + bv.x + av.x; rv.y = ar[m][1] + bv.y + av.y;
            rv.z = ar[m][2] + bv.z + av.z; rv.w = ar[m][3] + bv.w + av.w;
            *(float4*)&out[(size_t)n * 16 + jg * 4] = rv;
        }
    }
}

extern "C" void kernel_launch(void* const* d_in, const int* in_sizes, int n_in,
                              void* d_out, int out_size, void* d_ws, size_t ws_size,
                              hipStream_t stream) {
    const float* x     = (const float*)d_in[0];
    const int*   edge  = (const int*)d_in[1];
    const float* ax    = (const float*)d_in[2];
    const float* lf    = (const float*)d_in[3];
    const float* W1rel = (const float*)d_in[4];
    const float* b1    = (const float*)d_in[5];
    const float* W1root= (const float*)d_in[6];
    const float* W2rel = (const float*)d_in[7];
    const float* b2    = (const float*)d_in[8];
    const float* W2root= (const float*)d_in[9];
    const float* W3rel = (const float*)d_in[10];
    const float* b3    = (const float*)d_in[11];
    const float* W3root= (const float*)d_in[12];
    float* out = (float*)d_out;

    const int N = in_sizes[0] / 48;
    const int E = in_sizes[1] / 2;
    const int nbuck = (N + BN - 1) / BN;
    const int chunk = (E + B_PART - 1) / B_PART;
    const int M = nbuck * B_PART;
    const int nb = (M + SCAN_CHUNK - 1) / SCAN_CHUNK;

    // fp32 tables
    const size_t oR1 = 0;
    const size_t oH1 = (size_t)N * 32;
    const size_t oR2 = (size_t)N * 64;
    const size_t oH2 = (size_t)N * 112;
    // bf16 t-tables (t2 rows padded to 64 shorts)
    const size_t oTB1 = 0;
    const size_t oTB2 = (size_t)N * 32;
    const size_t oTB3 = (size_t)N * 96;

    // CSR build (radix partition, no global atomics)
    k_bcount<<<B_PART, 1024, 0, stream>>>(edge, E, nbuck, chunk);
    k_scan_local<<<nb, 256, 0, stream>>>(M);
    k_scan_bsums<<<1, 1024, 0, stream>>>(nb);
    k_bpart<<<B_PART, 1024, 0, stream>>>(edge, E, nbuck, chunk);
    k_csr<<<nbuck, BN, 0, stream>>>(N, E, nbuck);

    // Layer 1
    k_l1_transform<<<(N + 127) / 128, 512, 0, stream>>>(x, ax, W1rel, W1root, b1, N, oTB1, oR1);
    k_gather_relu<32, 32, 4><<<(unsigned)(((size_t)N * 4 + 255) / 256), 256, 0, stream>>>(oTB1, oR1, oH1, N);
    // Layer 2
    k_l2_transform<<<(N + 63) / 64, 384, 0, stream>>>(lf, W2rel, W2root, b2, N, oH1, oTB2, oR2);
    k_gather_relu<48, 64, 8><<<(unsigned)(((size_t)N * 6 + 255) / 256), 256, 0, stream>>>(oTB2, oR2, oH2, N);
    // Layer 3
    k_l3_transform<<<(N + 127) / 128, 256, 0, stream>>>(ax, W3rel, W3root, b3, N, oH2, oTB3, out);
    k_gather_out<<<(unsigned)(((size_t)N * 2 + 255) / 256), 256, 0, stream>>>(oTB3, out, N);
}

// Round 15
// 275.798 us; speedup vs baseline: 1.2166x; 1.0542x over previous
//
#include <hip/hip_runtime.h>

#define NODES_MAX 100000
#define EDGES_MAX 1600000
#define BN 256                                   // nodes per bucket (pow2)
#define NBUCK ((NODES_MAX + BN - 1) / BN)        // 391
#define B_PART 256                               // partition blocks (fixed)
#define SCAN_CHUNK 1024

// fp32 scratch (r/h tables): r1:0(32) h1:N*32(32) r2:N*64(48) h2:N*112(48)
__device__ float g_ws[(size_t)NODES_MAX * 160];
// bf16 t-tables: t1:0 (32/node) | t2:N*32 (64/node, 48 used: 128B-aligned rows) | t3:N*96 (16/node)
__device__ unsigned short g_tb[(size_t)NODES_MAX * 112];
__device__ int g_rowptr[NODES_MAX + 1];
__device__ int g_csr[EDGES_MAX];            // src ids grouped by dst
__device__ unsigned g_be[EDGES_MAX];        // bucket-ordered packed (src<<8)|local_dst
__device__ int g_mat[NBUCK * B_PART];       // per-(bucket,block) counts -> local-excl prefixes
__device__ int g_bsum[(NBUCK * B_PART + SCAN_CHUNK - 1) / SCAN_CHUNK + 1];

__device__ __forceinline__ unsigned short f2bf(float f) {
    union { float f; unsigned u; } c; c.f = f;
    unsigned r = (c.u + 0x7FFFu + ((c.u >> 16) & 1u)) >> 16;
    return (unsigned short)r;
}
__device__ __forceinline__ float bflo(unsigned u) {
    union { unsigned u; float f; } c; c.u = u << 16; return c.f;
}
__device__ __forceinline__ float bfhi(unsigned u) {
    union { unsigned u; float f; } c; c.u = u & 0xFFFF0000u; return c.f;
}

// ---------------- CSR build (radix partition, no global atomics) ----------------
__global__ __launch_bounds__(1024) void k_bcount(const int* __restrict__ edge, int E,
                                                 int nbuck, int chunk) {
    __shared__ int h[NBUCK];
    for (int i = threadIdx.x; i < nbuck; i += 1024) h[i] = 0;
    __syncthreads();
    const int lo = blockIdx.x * chunk, hi = min(E, lo + chunk);
    for (int e = lo + threadIdx.x; e < hi; e += 1024)
        atomicAdd(&h[edge[E + e] >> 8], 1);
    __syncthreads();
    for (int k = threadIdx.x; k < nbuck; k += 1024)
        g_mat[k * B_PART + blockIdx.x] = h[k];
}

__global__ __launch_bounds__(256) void k_scan_local(int M) {
    __shared__ int ssum[256];
    const int tid = threadIdx.x;
    const int base = blockIdx.x * SCAN_CHUNK + tid * 4;
    int v0 = (base + 0 < M) ? g_mat[base + 0] : 0;
    int v1 = (base + 1 < M) ? g_mat[base + 1] : 0;
    int v2 = (base + 2 < M) ? g_mat[base + 2] : 0;
    int v3 = (base + 3 < M) ? g_mat[base + 3] : 0;
    int s = v0 + v1 + v2 + v3;
    ssum[tid] = s;
    __syncthreads();
    for (int off = 1; off < 256; off <<= 1) {
        int v = (tid >= off) ? ssum[tid - off] : 0;
        __syncthreads();
        ssum[tid] += v;
        __syncthreads();
    }
    int run = ssum[tid] - s;
    if (base + 0 < M) g_mat[base + 0] = run;
    run += v0;
    if (base + 1 < M) g_mat[base + 1] = run;
    run += v1;
    if (base + 2 < M) g_mat[base + 2] = run;
    run += v2;
    if (base + 3 < M) g_mat[base + 3] = run;
    if (tid == 255) g_bsum[blockIdx.x] = ssum[255];
}

__global__ __launch_bounds__(1024) void k_scan_bsums(int nb) {
    __shared__ int ssum[1024];
    const int tid = threadIdx.x;
    int s = (tid < nb) ? g_bsum[tid] : 0;
    ssum[tid] = s;
    __syncthreads();
    for (int off = 1; off < 1024; off <<= 1) {
        int v = (tid >= off) ? ssum[tid - off] : 0;
        __syncthreads();
        ssum[tid] += v;
        __syncthreads();
    }
    if (tid < nb) g_bsum[tid] = ssum[tid] - s;
}

// Phase 3: re-read chunk, rank via LDS cursors (global offsets folded in here).
__global__ __launch_bounds__(1024) void k_bpart(const int* __restrict__ edge, int E,
                                                int nbuck, int chunk) {
    __shared__ int cur[NBUCK];
    for (int k = threadIdx.x; k < nbuck; k += 1024) {
        int idx = k * B_PART + blockIdx.x;
        cur[k] = g_mat[idx] + g_bsum[idx >> 10];
    }
    __syncthreads();
    const int lo = blockIdx.x * chunk, hi = min(E, lo + chunk);
    for (int e = lo + threadIdx.x; e < hi; e += 1024) {
        int s = edge[e], d = edge[E + e];
        int pos = atomicAdd(&cur[d >> 8], 1);
        g_be[pos] = ((unsigned)s << 8) | (unsigned)(d & (BN - 1));
    }
}

// One workgroup per bucket: LDS hist + scan -> rowptr, then bucket-local CSR scatter.
__global__ __launch_bounds__(BN) void k_csr(int N, int E, int nbuck) {
    const int b = blockIdx.x;
    const int nlo = b * BN;
    const int ebase = g_mat[b * B_PART] + g_bsum[(b * B_PART) >> 10];
    const int eend = (b + 1 < nbuck)
        ? (g_mat[(b + 1) * B_PART] + g_bsum[((b + 1) * B_PART) >> 10]) : E;
    __shared__ int cnt[BN];
    __shared__ int pfx[BN];
    const int tid = threadIdx.x;
    cnt[tid] = 0;
    __syncthreads();
    for (int e = ebase + tid; e < eend; e += BN)
        atomicAdd(&cnt[g_be[e] & (BN - 1)], 1);
    __syncthreads();
    int v = cnt[tid];
    pfx[tid] = v;
    __syncthreads();
    for (int off = 1; off < BN; off <<= 1) {
        int t = (tid >= off) ? pfx[tid - off] : 0;
        __syncthreads();
        pfx[tid] += t;
        __syncthreads();
    }
    int excl = pfx[tid] - v;
    int n = nlo + tid;
    if (n < N) g_rowptr[n] = ebase + excl;
    if (b == 0 && tid == 0) g_rowptr[N] = E;
    cnt[tid] = excl;  // reuse as cursor
    __syncthreads();
    for (int e = ebase + tid; e < eend; e += BN) {
        unsigned pv = g_be[e];
        int pos = atomicAdd(&cnt[pv & (BN - 1)], 1);
        g_csr[ebase + pos] = (int)(pv >> 8);
    }
}

// ---------------- gathers (bf16 rows, fp32 accumulate, 4x unrolled; R12-proven) ----
// F = features summed (8 per lane), RS = row stride in shorts (row alignment).
template <int F, int RS>
__global__ __launch_bounds__(256) void k_gather_relu(size_t oTB, size_t oR, size_t oH, int N) {
    constexpr int L = F / 8;
    int tid = blockIdx.x * 256 + threadIdx.x;
    int node = tid / L, c = tid % L;
    if (node >= N) return;
    const unsigned short* __restrict__ tb = &g_tb[oTB];
    int j = g_rowptr[node];
    const int end = g_rowptr[node + 1];
    float s0 = 0.f, s1 = 0.f, s2 = 0.f, s3 = 0.f, s4 = 0.f, s5 = 0.f, s6 = 0.f, s7 = 0.f;
    for (; j + 3 < end; j += 4) {
        int sn0 = g_csr[j], sn1 = g_csr[j + 1], sn2 = g_csr[j + 2], sn3 = g_csr[j + 3];
        const uint4 v0 = *(const uint4*)&tb[(size_t)sn0 * RS + c * 8];
        const uint4 v1 = *(const uint4*)&tb[(size_t)sn1 * RS + c * 8];
        const uint4 v2 = *(const uint4*)&tb[(size_t)sn2 * RS + c * 8];
        const uint4 v3 = *(const uint4*)&tb[(size_t)sn3 * RS + c * 8];
        s0 += bflo(v0.x) + bflo(v1.x) + bflo(v2.x) + bflo(v3.x);
        s1 += bfhi(v0.x) + bfhi(v1.x) + bfhi(v2.x) + bfhi(v3.x);
        s2 += bflo(v0.y) + bflo(v1.y) + bflo(v2.y) + bflo(v3.y);
        s3 += bfhi(v0.y) + bfhi(v1.y) + bfhi(v2.y) + bfhi(v3.y);
        s4 += bflo(v0.z) + bflo(v1.z) + bflo(v2.z) + bflo(v3.z);
        s5 += bfhi(v0.z) + bfhi(v1.z) + bfhi(v2.z) + bfhi(v3.z);
        s6 += bflo(v0.w) + bflo(v1.w) + bflo(v2.w) + bflo(v3.w);
        s7 += bfhi(v0.w) + bfhi(v1.w) + bfhi(v2.w) + bfhi(v3.w);
    }
    for (; j < end; ++j) {
        int sn = g_csr[j];
        const uint4 v = *(const uint4*)&tb[(size_t)sn * RS + c * 8];
        s0 += bflo(v.x); s1 += bfhi(v.x);
        s2 += bflo(v.y); s3 += bfhi(v.y);
        s4 += bflo(v.z); s5 += bfhi(v.z);
        s6 += bflo(v.w); s7 += bfhi(v.w);
    }
    const size_t ro = oR + (size_t)node * F + c * 8;
    const float4 ra = *(const float4*)&g_ws[ro];
    const float4 rb = *(const float4*)&g_ws[ro + 4];
    float4 oa, ob;
    oa.x = fmaxf(s0 + ra.x, 0.f); oa.y = fmaxf(s1 + ra.y, 0.f);
    oa.z = fmaxf(s2 + ra.z, 0.f); oa.w = fmaxf(s3 + ra.w, 0.f);
    ob.x = fmaxf(s4 + rb.x, 0.f); ob.y = fmaxf(s5 + rb.y, 0.f);
    ob.z = fmaxf(s6 + rb.z, 0.f); ob.w = fmaxf(s7 + rb.w, 0.f);
    const size_t ho = oH + (size_t)node * F + c * 8;
    *(float4*)&g_ws[ho] = oa;
    *(float4*)&g_ws[ho + 4] = ob;
}

__global__ __launch_bounds__(256) void k_gather_out(size_t oTB, float* __restrict__ out, int N) {
    constexpr int F = 16, L = 2;
    int tid = blockIdx.x * 256 + threadIdx.x;
    int node = tid / L, c = tid % L;
    if (node >= N) return;
    const unsigned short* __restrict__ tb = &g_tb[oTB];
    int j = g_rowptr[node];
    const int end = g_rowptr[node + 1];
    float s0 = 0.f, s1 = 0.f, s2 = 0.f, s3 = 0.f, s4 = 0.f, s5 = 0.f, s6 = 0.f, s7 = 0.f;
    for (; j + 3 < end; j += 4) {
        int sn0 = g_csr[j], sn1 = g_csr[j + 1], sn2 = g_csr[j + 2], sn3 = g_csr[j + 3];
        const uint4 v0 = *(const uint4*)&tb[(size_t)sn0 * F + c * 8];
        const uint4 v1 = *(const uint4*)&tb[(size_t)sn1 * F + c * 8];
        const uint4 v2 = *(const uint4*)&tb[(size_t)sn2 * F + c * 8];
        const uint4 v3 = *(const uint4*)&tb[(size_t)sn3 * F + c * 8];
        s0 += bflo(v0.x) + bflo(v1.x) + bflo(v2.x) + bflo(v3.x);
        s1 += bfhi(v0.x) + bfhi(v1.x) + bfhi(v2.x) + bfhi(v3.x);
        s2 += bflo(v0.y) + bflo(v1.y) + bflo(v2.y) + bflo(v3.y);
        s3 += bfhi(v0.y) + bfhi(v1.y) + bfhi(v2.y) + bfhi(v3.y);
        s4 += bflo(v0.z) + bflo(v1.z) + bflo(v2.z) + bflo(v3.z);
        s5 += bfhi(v0.z) + bfhi(v1.z) + bfhi(v2.z) + bfhi(v3.z);
        s6 += bflo(v0.w) + bflo(v1.w) + bflo(v2.w) + bflo(v3.w);
        s7 += bfhi(v0.w) + bfhi(v1.w) + bfhi(v2.w) + bfhi(v3.w);
    }
    for (; j < end; ++j) {
        int sn = g_csr[j];
        const uint4 v = *(const uint4*)&tb[(size_t)sn * F + c * 8];
        s0 += bflo(v.x); s1 += bfhi(v.x);
        s2 += bflo(v.y); s3 += bfhi(v.y);
        s4 += bflo(v.z); s5 += bfhi(v.z);
        s6 += bflo(v.w); s7 += bfhi(v.w);
    }
    float* op = &out[(size_t)node * F + c * 8];
    float4 oa = *(float4*)op;
    float4 ob = *(float4*)(op + 4);
    oa.x += s0; oa.y += s1; oa.z += s2; oa.w += s3;
    ob.x += s4; ob.y += s5; ob.z += s6; ob.w += s7;
    *(float4*)op = oa;
    *(float4*)(op + 4) = ob;
}

// ---------------- transforms (LDS-tiled, occupancy-tuned; R11-proven) ----------------
// L1: 512 thr, 128 nodes/block, sH bf16 (pad 72), 8 jg x 64 nlp, 2 nodes/thread.
#define L1_PADS 72
__global__ __launch_bounds__(512) void k_l1_transform(
        const float* __restrict__ x, const float* __restrict__ ax,
        const float* __restrict__ Wrel, const float* __restrict__ Wroot,
        const float* __restrict__ b, int N, size_t oTB1, size_t oR1) {
    __shared__ float sWrel[64 * 32];
    __shared__ float sWroot[64 * 32];
    __shared__ unsigned short sH[128 * L1_PADS];
    const int tid = threadIdx.x;
    if (tid < 512) {
        ((float4*)sWrel)[tid] = ((const float4*)Wrel)[tid];
        ((float4*)sWroot)[tid] = ((const float4*)Wroot)[tid];
    }
    const int n0 = blockIdx.x * 128;
    for (int i = tid; i < 128 * 16; i += 512) {
        int nl = i >> 4, g = i & 15, n = n0 + nl;
        float4 v = {0.f, 0.f, 0.f, 0.f};
        if (n < N) v = (g < 12) ? *(const float4*)&x[(size_t)n * 48 + g * 4]
                                : *(const float4*)&ax[(size_t)n * 16 + (g - 12) * 4];
        ushort4 hv;
        hv.x = f2bf(v.x); hv.y = f2bf(v.y); hv.z = f2bf(v.z); hv.w = f2bf(v.w);
        *(ushort4*)&sH[nl * L1_PADS + g * 4] = hv;
    }
    __syncthreads();
    const int jg = tid & 7, nlp = tid >> 3;   // 8 jg x 64 nlp
    const unsigned short* h0p = &sH[(nlp * 2 + 0) * L1_PADS];
    const unsigned short* h1p = &sH[(nlp * 2 + 1) * L1_PADS];
    float at[2][4] = {}, ar[2][4] = {};
    for (int k = 0; k < 64; ++k) {
        const float4 wr = *(const float4*)&sWrel[k * 32 + jg * 4];
        const float4 wo = *(const float4*)&sWroot[k * 32 + jg * 4];
        const float h0 = bflo(h0p[k]);
        const float h1 = bflo(h1p[k]);
        at[0][0] = fmaf(h0, wr.x, at[0][0]); at[0][1] = fmaf(h0, wr.y, at[0][1]);
        at[0][2] = fmaf(h0, wr.z, at[0][2]); at[0][3] = fmaf(h0, wr.w, at[0][3]);
        ar[0][0] = fmaf(h0, wo.x, ar[0][0]); ar[0][1] = fmaf(h0, wo.y, ar[0][1]);
        ar[0][2] = fmaf(h0, wo.z, ar[0][2]); ar[0][3] = fmaf(h0, wo.w, ar[0][3]);
        at[1][0] = fmaf(h1, wr.x, at[1][0]); at[1][1] = fmaf(h1, wr.y, at[1][1]);
        at[1][2] = fmaf(h1, wr.z, at[1][2]); at[1][3] = fmaf(h1, wr.w, at[1][3]);
        ar[1][0] = fmaf(h1, wo.x, ar[1][0]); ar[1][1] = fmaf(h1, wo.y, ar[1][1]);
        ar[1][2] = fmaf(h1, wo.z, ar[1][2]); ar[1][3] = fmaf(h1, wo.w, ar[1][3]);
    }
    const float4 bv = *(const float4*)&b[jg * 4];
    #pragma unroll
    for (int m = 0; m < 2; ++m) {
        int n = n0 + nlp * 2 + m;
        if (n < N) {
            ushort4 tv;
            tv.x = f2bf(at[m][0]); tv.y = f2bf(at[m][1]);
            tv.z = f2bf(at[m][2]); tv.w = f2bf(at[m][3]);
            *(ushort4*)&g_tb[oTB1 + (size_t)n * 32 + jg * 4] = tv;
            float4 rv;
            rv.x = ar[m][0] + bv.x; rv.y = ar[m][1] + bv.y;
            rv.z = ar[m][2] + bv.z; rv.w = ar[m][3] + bv.w;
            *(float4*)&g_ws[oR1 + (size_t)n * 32 + jg * 4] = rv;
        }
    }
}

// L2: 384 thr, 64 nodes/block, fp32 sH (pad 49), 12 jg x 32 nlp, 2 nodes/thread.
// t2 rows padded to 64 shorts (128 B) for single-line gathers.
#define L2_PAD 49
__global__ __launch_bounds__(384) void k_l2_transform(
        const float* __restrict__ lf,
        const float* __restrict__ Wrel, const float* __restrict__ Wroot,
        const float* __restrict__ b, int N,
        size_t oH1, size_t oTB2, size_t oR2) {
    __shared__ float sWrel[48 * 48];
    __shared__ float sWroot[48 * 48];
    __shared__ float sH[64 * L2_PAD];
    const int tid = threadIdx.x;
    for (int i = tid; i < 576; i += 384) {
        ((float4*)sWrel)[i] = ((const float4*)Wrel)[i];
        ((float4*)sWroot)[i] = ((const float4*)Wroot)[i];
    }
    const int n0 = blockIdx.x * 64;
    for (int i = tid; i < 64 * 48; i += 384) {
        int nl = i / 48, k = i % 48, n = n0 + nl;
        float v = 0.f;
        if (n < N) v = (k < 32) ? g_ws[oH1 + (size_t)n * 32 + k]
                                : lf[(size_t)n * 16 + (k - 32)];
        sH[nl * L2_PAD + k] = v;
    }
    __syncthreads();
    const int jg = tid % 12, nlp = tid / 12;  // 12 jg x 32 nlp
    const float* h0p = &sH[(nlp * 2 + 0) * L2_PAD];
    const float* h1p = &sH[(nlp * 2 + 1) * L2_PAD];
    float at[2][4] = {}, ar[2][4] = {};
    for (int k = 0; k < 48; ++k) {
        const float4 wr = *(const float4*)&sWrel[k * 48 + jg * 4];
        const float4 wo = *(const float4*)&sWroot[k * 48 + jg * 4];
        const float h0 = h0p[k];
        const float h1 = h1p[k];
        at[0][0] = fmaf(h0, wr.x, at[0][0]); at[0][1] = fmaf(h0, wr.y, at[0][1]);
        at[0][2] = fmaf(h0, wr.z, at[0][2]); at[0][3] = fmaf(h0, wr.w, at[0][3]);
        ar[0][0] = fmaf(h0, wo.x, ar[0][0]); ar[0][1] = fmaf(h0, wo.y, ar[0][1]);
        ar[0][2] = fmaf(h0, wo.z, ar[0][2]); ar[0][3] = fmaf(h0, wo.w, ar[0][3]);
        at[1][0] = fmaf(h1, wr.x, at[1][0]); at[1][1] = fmaf(h1, wr.y, at[1][1]);
        at[1][2] = fmaf(h1, wr.z, at[1][2]); at[1][3] = fmaf(h1, wr.w, at[1][3]);
        ar[1][0] = fmaf(h1, wo.x, ar[1][0]); ar[1][1] = fmaf(h1, wo.y, ar[1][1]);
        ar[1][2] = fmaf(h1, wo.z, ar[1][2]); ar[1][3] = fmaf(h1, wo.w, ar[1][3]);
    }
    const float4 bv = *(const float4*)&b[jg * 4];
    #pragma unroll
    for (int m = 0; m < 2; ++m) {
        int n = n0 + nlp * 2 + m;
        if (n < N) {
            ushort4 tv;
            tv.x = f2bf(at[m][0]); tv.y = f2bf(at[m][1]);
            tv.z = f2bf(at[m][2]); tv.w = f2bf(at[m][3]);
            *(ushort4*)&g_tb[oTB2 + (size_t)n * 64 + jg * 4] = tv;   // stride 64 (padded)
            float4 rv;
            rv.x = ar[m][0] + bv.x; rv.y = ar[m][1] + bv.y;
            rv.z = ar[m][2] + bv.z; rv.w = ar[m][3] + bv.w;
            *(float4*)&g_ws[oR2 + (size_t)n * 48 + jg * 4] = rv;
        }
    }
}

// L3: 256 thr, 128 nodes/block, fp32 sH (pad 49), 4 jg x 64 nlp, 2 nodes/thread.
#define L3_PAD 49
__global__ __launch_bounds__(256) void k_l3_transform(
        const float* __restrict__ ax,
        const float* __restrict__ Wrel, const float* __restrict__ Wroot,
        const float* __restrict__ b, int N,
        size_t oH2, size_t oTB3, float* __restrict__ out) {
    __shared__ float sWrel[48 * 16];
    __shared__ float sWroot[48 * 16];
    __shared__ float sH[128 * L3_PAD];
    const int tid = threadIdx.x;
    if (tid < 192) {
        ((float4*)sWrel)[tid] = ((const float4*)Wrel)[tid];
        ((float4*)sWroot)[tid] = ((const float4*)Wroot)[tid];
    }
    const int n0 = blockIdx.x * 128;
    for (int i = tid; i < 128 * 48; i += 256) {
        int nl = i / 48, k = i % 48, n = n0 + nl;
        sH[nl * L3_PAD + k] = (n < N) ? g_ws[oH2 + (size_t)n * 48 + k] : 0.f;
    }
    __syncthreads();
    const int jg = tid & 3, nlp = tid >> 2;   // 4 jg x 64 nlp
    const float* h0p = &sH[(nlp * 2 + 0) * L3_PAD];
    const float* h1p = &sH[(nlp * 2 + 1) * L3_PAD];
    float at[2][4] = {}, ar[2][4] = {};
    for (int k = 0; k < 48; ++k) {
        const float4 wr = *(const float4*)&sWrel[k * 16 + jg * 4];
        const float4 wo = *(const float4*)&sWroot[k * 16 + jg * 4];
        const float h0 = h0p[k];
        const float h1 = h1p[k];
        at[0][0] = fmaf(h0, wr.x, at[0][0]); at[0][1] = fmaf(h0, wr.y, at[0][1]);
        at[0][2] = fmaf(h0, wr.z, at[0][2]); at[0][3] = fmaf(h0, wr.w, at[0][3]);
        ar[0][0] = fmaf(h0, wo.x, ar[0][0]); ar[0][1] = fmaf(h0, wo.y, ar[0][1]);
        ar[0][2] = fmaf(h0, wo.z, ar[0][2]); ar[0][3] = fmaf(h0, wo.w, ar[0][3]);
        at[1][0] = fmaf(h1, wr.x, at[1][0]); at[1][1] = fmaf(h1, wr.y, at[1][1]);
        at[1][2] = fmaf(h1, wr.z, at[1][2]); at[1][3] = fmaf(h1, wr.w, at[1][3]);
        ar[1][0] = fmaf(h1, wo.x, ar[1][0]); ar[1][1] = fmaf(h1, wo.y, ar[1][1]);
        ar[1][2] = fmaf(h1, wo.z, ar[1][2]); ar[1][3] = fmaf(h1, wo.w, ar[1][3]);
    }
    const float4 bv = *(const float4*)&b[jg * 4];
    #pragma unroll
    for (int m = 0; m < 2; ++m) {
        int n = n0 + nlp * 2 + m;
        if (n < N) {
            ushort4 tv;
            tv.x = f2bf(at[m][0]); tv.y = f2bf(at[m][1]);
            tv.z = f2bf(at[m][2]); tv.w = f2bf(at[m][3]);
            *(ushort4*)&g_tb[oTB3 + (size_t)n * 16 + jg * 4] = tv;
            const float4 av = *(const float4*)&ax[(size_t)n * 16 + jg * 4];
            float4 rv;
            rv.x = ar[m][0] + bv.x + av.x; rv.y = ar[m][1] + bv.y + av.y;
            rv.z = ar[m][2] + bv.z + av.z; rv.w = ar[m][3] + bv.w + av.w;
            *(float4*)&out[(size_t)n * 16 + jg * 4] = rv;
        }
    }
}

extern "C" void kernel_launch(void* const* d_in, const int* in_sizes, int n_in,
                              void* d_out, int out_size, void* d_ws, size_t ws_size,
                              hipStream_t stream) {
    const float* x     = (const float*)d_in[0];
    const int*   edge  = (const int*)d_in[1];
    const float* ax    = (const float*)d_in[2];
    const float* lf    = (const float*)d_in[3];
    const float* W1rel = (const float*)d_in[4];
    const float* b1    = (const float*)d_in[5];
    const float* W1root= (const float*)d_in[6];
    const float* W2rel = (const float*)d_in[7];
    const float* b2    = (const float*)d_in[8];
    const float* W2root= (const float*)d_in[9];
    const float* W3rel = (const float*)d_in[10];
    const float* b3    = (const float*)d_in[11];
    const float* W3root= (const float*)d_in[12];
    float* out = (float*)d_out;

    const int N = in_sizes[0] / 48;
    const int E = in_sizes[1] / 2;
    const int nbuck = (N + BN - 1) / BN;
    const int chunk = (E + B_PART - 1) / B_PART;
    const int M = nbuck * B_PART;
    const int nb = (M + SCAN_CHUNK - 1) / SCAN_CHUNK;

    // fp32 tables
    const size_t oR1 = 0;
    const size_t oH1 = (size_t)N * 32;
    const size_t oR2 = (size_t)N * 64;
    const size_t oH2 = (size_t)N * 112;
    // bf16 t-tables (t2 rows padded to 64 shorts)
    const size_t oTB1 = 0;
    const size_t oTB2 = (size_t)N * 32;
    const size_t oTB3 = (size_t)N * 96;

    // CSR build (radix partition, no global atomics)
    k_bcount<<<B_PART, 1024, 0, stream>>>(edge, E, nbuck, chunk);
    k_scan_local<<<nb, 256, 0, stream>>>(M);
    k_scan_bsums<<<1, 1024, 0, stream>>>(nb);
    k_bpart<<<B_PART, 1024, 0, stream>>>(edge, E, nbuck, chunk);
    k_csr<<<nbuck, BN, 0, stream>>>(N, E, nbuck);

    // Layer 1
    k_l1_transform<<<(N + 127) / 128, 512, 0, stream>>>(x, ax, W1rel, W1root, b1, N, oTB1, oR1);
    k_gather_relu<32, 32><<<(unsigned)(((size_t)N * 4 + 255) / 256), 256, 0, stream>>>(oTB1, oR1, oH1, N);
    // Layer 2
    k_l2_transform<<<(N + 63) / 64, 384, 0, stream>>>(lf, W2rel, W2root, b2, N, oH1, oTB2, oR2);
    k_gather_relu<48, 64><<<(unsigned)(((size_t)N * 6 + 255) / 256), 256, 0, stream>>>(oTB2, oR2, oH2, N);
    // Layer 3
    k_l3_transform<<<(N + 127) / 128, 256, 0, stream>>>(ax, W3rel, W3root, b3, N, oH2, oTB3, out);
    k_gather_out<<<(unsigned)(((size_t)N * 2 + 255) / 256), 256, 0, stream>>>(oTB3, out, N);
}